// Round 4
// baseline (179.786 us; speedup 1.0000x reference)
//
#include <hip/hip_runtime.h>
#include <float.h>

#define NC    256
#define FHH   256
#define FWW   256
#define NOUT  7
#define NCELL 49
#define NSAMP (NCELL * 4)   // 196 pre-pool samples per roi

// One block per roi.
// Stage 1 (tid<196): per-sample records (clipped offsets, valid-premultiplied
//   bilinear weights), exact reference op sequence.
// Stage 1.5 (tid<49): compact valid sample list per cell + m_init
//   (invalid sample contributes exactly 0.0f to the max).
// Stage 2 (tid=channel): per cell, loop ONLY valid samples; stage to LDS.
// Stage 3: coalesced float4 write of the roi's contiguous 50176-float region.
__global__ __launch_bounds__(256) void rroi_pool_roi_kernel(
    const float* __restrict__ feat, const float* __restrict__ rois,
    float* __restrict__ out)
{
    __shared__ int4   s_off[NSAMP];
    __shared__ float4 s_wt[NSAMP];
    __shared__ int    s_any[NSAMP];
    __shared__ int    s_idx[NSAMP];    // compacted valid sample ids, per cell
    __shared__ int    s_cnt[NCELL];
    __shared__ float  s_init[NCELL];
    __shared__ float  s_out[NC * NCELL];   // 49 KiB

    const int n = blockIdx.x;
    const int tid = threadIdx.x;
    const float* __restrict__ r = rois + (size_t)n * 6;

    if (tid < NSAMP) {
        const int cell = tid >> 2;
        const int sub  = tid & 3;
        const int ph = cell / NOUT, pw = cell % NOUT;
        const int dy = sub >> 1,    dx = sub & 1;
        const int gy = 2 * ph + dy;
        const int gx = 2 * pw + dx;

        const float x1 = r[1], y1 = r[2], x2 = r[3], y2 = r[4], th = r[5];
        const float cx = (x1 + x2) * 0.5f;
        const float cy = (y1 + y2) * 0.5f;
        const float w  = x2 - x1;
        const float h  = y2 - y1;
        const float cos_t = cosf(th), sin_t = sinf(th);
        const float awx =  cos_t * w * 0.5f;
        const float bwy =  sin_t * h * 0.5f;
        const float cwx = -sin_t * w * 0.5f;
        const float dwy =  cos_t * h * 0.5f;

        const float uy = (2.0f * (float)gy + 1.0f) / 14.0f - 1.0f;
        const float ux = (2.0f * (float)gx + 1.0f) / 14.0f - 1.0f;

        const float px = cx + 16.0f * (awx * ux + bwy * uy);
        const float py = cy + 16.0f * (cwx * ux + dwy * uy);

        // replicate reference op sequence exactly
        const float gxn = 2.0f * px / 256.0f - 1.0f;
        const float gyn = 2.0f * py / 256.0f - 1.0f;
        const float ixf = ((gxn + 1.0f) * 256.0f - 1.0f) * 0.5f;
        const float iyf = ((gyn + 1.0f) * 256.0f - 1.0f) * 0.5f;

        const float ix0f = floorf(ixf);
        const float iy0f = floorf(iyf);
        const float wx = ixf - ix0f;
        const float wy = iyf - iy0f;
        const int ix0 = (int)ix0f;
        const int iy0 = (int)iy0f;
        const int ix1 = ix0 + 1;
        const int iy1 = iy0 + 1;

        const bool vx0 = (ix0 >= 0) & (ix0 < FWW);
        const bool vx1 = (ix1 >= 0) & (ix1 < FWW);
        const bool vy0 = (iy0 >= 0) & (iy0 < FHH);
        const bool vy1 = (iy1 >= 0) & (iy1 < FHH);

        const int xc0 = min(max(ix0, 0), FWW - 1);
        const int xc1 = min(max(ix1, 0), FWW - 1);
        const int yc0 = min(max(iy0, 0), FHH - 1);
        const int yc1 = min(max(iy1, 0), FHH - 1);

        s_off[tid] = make_int4(yc0 * FWW + xc0, yc0 * FWW + xc1,
                               yc1 * FWW + xc0, yc1 * FWW + xc1);
        s_wt[tid] = make_float4(((1.0f - wy) * (1.0f - wx)) * (float)(vy0 & vx0),
                                ((1.0f - wy) * wx)          * (float)(vy0 & vx1),
                                (wy * (1.0f - wx))          * (float)(vy1 & vx0),
                                (wy * wx)                   * (float)(vy1 & vx1));
        s_any[tid] = (int)((vy0 | vy1) & (vx0 | vx1));
    }
    __syncthreads();

    // stage 1.5: per-cell compaction (threads 0..48)
    if (tid < NCELL) {
        int cnt = 0;
        int inv = 0;
#pragma unroll
        for (int sub = 0; sub < 4; ++sub) {
            const int s = tid * 4 + sub;
            if (s_any[s]) s_idx[tid * 4 + cnt++] = s;
            else          inv = 1;
        }
        s_cnt[tid]  = cnt;
        s_init[tid] = inv ? 0.0f : -FLT_MAX;
    }
    __syncthreads();

    // stage 2: one channel per thread; only valid samples gathered
    const int c = tid;
    const int idx = (int)r[0];
    const float* __restrict__ img =
        feat + ((size_t)idx * NC + c) * (size_t)(FHH * FWW);

    for (int cell = 0; cell < NCELL; ++cell) {
        const int nv = s_cnt[cell];     // LDS broadcast, block-uniform
        float m = s_init[cell];
        for (int k = 0; k < nv; ++k) {  // uniform trip count, usually 0
            const int s = s_idx[cell * 4 + k];
            const int4   o  = s_off[s];
            const float4 wv = s_wt[s];
            const float val = img[o.x] * wv.x + img[o.y] * wv.y
                            + img[o.z] * wv.z + img[o.w] * wv.w;
            m = fmaxf(m, val);
        }
        s_out[c * NCELL + cell] = m;
    }
    __syncthreads();

    // stage 3: coalesced float4 write of contiguous 50176-float region
    float4* __restrict__ dst = (float4*)(out + (size_t)n * (NC * NCELL));
    const float4* __restrict__ src = (const float4*)s_out;
#pragma unroll
    for (int i = tid; i < (NC * NCELL) / 4; i += 256)
        dst[i] = src[i];
}

extern "C" void kernel_launch(void* const* d_in, const int* in_sizes, int n_in,
                              void* d_out, int out_size, void* d_ws, size_t ws_size,
                              hipStream_t stream) {
    const float* feat = (const float*)d_in[0];
    const float* rois = (const float*)d_in[1];
    float* out = (float*)d_out;
    const int nrois = in_sizes[1] / 6;   // 512
    rroi_pool_roi_kernel<<<nrois, 256, 0, stream>>>(feat, rois, out);
}